// Round 15
// baseline (356.779 us; speedup 1.0000x reference)
//
#include <hip/hip_runtime.h>

// Transformer block forward, MI355X gfx950.
// B=4, T=2048, D=1024, H=16, DH=64. bf16 MFMA compute, bf16 intermediates.

#define B_ 4
#define T_ 2048
#define D_ 1024
#define H_ 16
#define DH_ 64

using u16 = unsigned short;
typedef short bf16x8 __attribute__((ext_vector_type(8)));   // 8 bf16 (4 VGPRs)
typedef float f32x4 __attribute__((ext_vector_type(4)));

#define GLOAD_LDS16(g, l)                                                          \
  __builtin_amdgcn_global_load_lds((const __attribute__((address_space(1))) void*)(g), \
                                   (__attribute__((address_space(3))) void*)(l), 16, 0, 0)

#define CVTPK(d, lo, hi) asm("v_cvt_pk_bf16_f32 %0, %1, %2" : "=v"(d) : "v"(lo), "v"(hi))
#define BARSB() do { __builtin_amdgcn_s_barrier(); __builtin_amdgcn_sched_barrier(0); } while (0)

__device__ __forceinline__ f32x4 mfma16(bf16x8 a, bf16x8 b, f32x4 c) {
  return __builtin_amdgcn_mfma_f32_16x16x32_bf16(a, b, c, 0, 0, 0);
}

__device__ __forceinline__ u16 f2bf(float f) {  // RNE f32->bf16
  union { float f; unsigned u; } v; v.f = f;
  unsigned r = v.u + 0x7fffu + ((v.u >> 16) & 1u);
  return (u16)(r >> 16);
}
__device__ __forceinline__ float bf2f(u16 h) {
  union { unsigned u; float f; } v; v.u = ((unsigned)h) << 16; return v.f;
}

// ---------------- LayerNorm: x[row][1024] (f32 or bf16) -> bf16 ----------------
template<typename TI>
__global__ __launch_bounds__(256)
void ln_kernel(const TI* __restrict__ x, const float* __restrict__ g,
               const float* __restrict__ be, u16* __restrict__ yb)
{
  const int row = blockIdx.x;
  const int tid = threadIdx.x;
  float v0, v1, v2, v3;
  if constexpr (sizeof(TI) == 4) {
    const float4 vx = ((const float4*)(x + (size_t)row * D_))[tid];
    v0 = vx.x; v1 = vx.y; v2 = vx.z; v3 = vx.w;
  } else {
    const ushort4 vx = ((const ushort4*)((const u16*)x + (size_t)row * D_))[tid];
    v0 = bf2f(vx.x); v1 = bf2f(vx.y); v2 = bf2f(vx.z); v3 = bf2f(vx.w);
  }
  float s  = v0 + v1 + v2 + v3;
  float s2 = v0*v0 + v1*v1 + v2*v2 + v3*v3;
#pragma unroll
  for (int m = 1; m < 64; m <<= 1) { s += __shfl_xor(s, m); s2 += __shfl_xor(s2, m); }
  __shared__ float red[8];
  const int w = tid >> 6;
  if ((tid & 63) == 0) { red[w] = s; red[4 + w] = s2; }
  __syncthreads();
  s  = red[0] + red[1] + red[2] + red[3];
  s2 = red[4] + red[5] + red[6] + red[7];
  const float mu   = s * (1.0f / D_);
  const float rstd = rsqrtf(s2 * (1.0f / D_) - mu * mu + 1e-5f);
  const float4 gg = ((const float4*)g)[tid];
  const float4 bb = ((const float4*)be)[tid];
  ushort4 pk;
  pk.x = f2bf((v0 - mu) * rstd * gg.x + bb.x);
  pk.y = f2bf((v1 - mu) * rstd * gg.y + bb.y);
  pk.z = f2bf((v2 - mu) * rstd * gg.z + bb.z);
  pk.w = f2bf((v3 - mu) * rstd * gg.w + bb.w);
  ((ushort4*)(yb + (size_t)row * D_))[tid] = pk;
}

// ------------- transpose + cvt: in f32 [R][C] -> out bf16 [C][R], per z-matrix -------------
__global__ __launch_bounds__(256)
void transpose_cvt(const float* __restrict__ in, u16* __restrict__ out, int R, int C)
{
  __shared__ float tile[32][33];
  const int c0 = blockIdx.x * 32, r0 = blockIdx.y * 32;
  const float* ip = in + (size_t)blockIdx.z * R * C;
  u16* op = out + (size_t)blockIdx.z * R * C;
  const int tx = threadIdx.x, ty = threadIdx.y;  // 32 x 8
#pragma unroll
  for (int j = 0; j < 4; ++j)
    tile[ty + j * 8][tx] = ip[(size_t)(r0 + ty + j * 8) * C + (c0 + tx)];
  __syncthreads();
#pragma unroll
  for (int j = 0; j < 4; ++j)
    op[(size_t)(c0 + ty + j * 8) * R + (r0 + tx)] = f2bf(tile[tx][ty + j * 8]);
}

// ------------- fused Wq/Wk/Wv transpose (R=1024, C=64; z = mat*16 + zz) -------------
__global__ __launch_bounds__(256)
void transpose_cvt3(const float* __restrict__ w0, const float* __restrict__ w1,
                    const float* __restrict__ w2, u16* __restrict__ out)
{
  __shared__ float tile[32][33];
  const int R = 1024, C = 64;
  const int mat = blockIdx.z >> 4, zz = blockIdx.z & 15;
  const float* in = (mat == 0) ? w0 : (mat == 1) ? w1 : w2;
  const int c0 = blockIdx.x * 32, r0 = blockIdx.y * 32;
  const float* ip = in + (size_t)zz * R * C;
  u16* op = out + (size_t)mat * 1048576 + (size_t)zz * R * C;
  const int tx = threadIdx.x, ty = threadIdx.y;
#pragma unroll
  for (int j = 0; j < 4; ++j)
    tile[ty + j * 8][tx] = ip[(size_t)(r0 + ty + j * 8) * C + (c0 + tx)];
  __syncthreads();
#pragma unroll
  for (int j = 0; j < 4; ++j)
    op[(size_t)(c0 + ty + j * 8) * R + (r0 + tx)] = f2bf(tile[tx][ty + j * 8]);
}

// ------------- bf16 transpose: in [R][C] -> out [C][R], per z-matrix -------------
__global__ __launch_bounds__(256)
void transpose_bf(const u16* __restrict__ in, u16* __restrict__ out, int R, int C)
{
  __shared__ u16 tile[32][34];
  const int c0 = blockIdx.x * 32, r0 = blockIdx.y * 32;
  const u16* ip = in + (size_t)blockIdx.z * R * C;
  u16* op = out + (size_t)blockIdx.z * R * C;
  const int tx = threadIdx.x, ty = threadIdx.y;
#pragma unroll
  for (int j = 0; j < 4; ++j)
    tile[ty + j * 8][tx] = ip[(size_t)(r0 + ty + j * 8) * C + (c0 + tx)];
  __syncthreads();
#pragma unroll
  for (int j = 0; j < 4; ++j)
    op[(size_t)(c0 + ty + j * 8) * R + (r0 + tx)] = tile[tx][ty + j * 8];
}

#define MODE_QKV 0
#define MODE_WP 1
#define MODE_MLP1 2
#define MODE_MLP2 3

// ---------------- gemm256v3: BM=256, BN=BR*64, BK=64, 8 waves, 2 phases/K-tile ----------
// BR=4 (BN=256) or BR=2 (BN=128). Ledger (loads/tile = 4+BR):
// entering tile i in-flight = A0,A2(t+1) [2]; ph1 +(2+BR); ph2 +2;
// tile-end vmcnt(2) confirms all of t+1, leaves A0,A2(t+2). Never drains mid-loop.
// Write-hazard: ph2's A0,A2(t+2) -> rows 0-63/128-191 of current buf, all read in ph1
// which ends with a barrier before ph2 issues. Safe.
template<int MODE, int BR>
__global__ __launch_bounds__(512, 2)
void gemm256v3(const u16* __restrict__ A, const u16* __restrict__ Bt,
               int M, int N, int K,
               const float* __restrict__ bias, const u16* __restrict__ resid,
               float* __restrict__ outf, u16* __restrict__ outb,
               u16* __restrict__ qo, u16* __restrict__ ko, u16* __restrict__ vo)
{
  __shared__ __align__(16) u16 Ash[2][256 * 64];
  __shared__ __align__(16) u16 Bsh[2][BR * 64 * 64];
  const int t = threadIdx.x, w = t >> 6, l = t & 63, lg = l >> 4, lr = l & 15;
  const int wr = w >> 2, wc = w & 3;

  const int gx = gridDim.x;
  const int nwg = gx * gridDim.y;
  const int bid = blockIdx.y * gx + blockIdx.x;
  const int cpx = nwg >> 3;
  const int virt = (bid & 7) * cpx + (bid >> 3);
  const int bn0 = (virt % gx) * (BR * 64), bm0 = (virt / gx) * 256;

  f32x4 acc[8][BR] = {};

  const int srow = t >> 3;
  const int sc16 = (t & 7) ^ (srow & 7);
  const u16* gAs = A  + (size_t)(bm0 + srow) * K + sc16 * 8;
  const u16* gBs = Bt + (size_t)(bn0 + srow) * K + sc16 * 8;

#define ISS2_A(R, BUF, ko) GLOAD_LDS16(gAs + (size_t)(R) * 64 * K + (ko), &Ash[BUF][(R) * 4096 + w * 512])
#define ISS2_B(R, BUF, ko) GLOAD_LDS16(gBs + (size_t)(R) * 64 * K + (ko), &Bsh[BUF][(R) * 4096 + w * 512])

  const int nkt = K >> 6;
  ISS2_A(0, 0, 0); ISS2_A(1, 0, 0); ISS2_A(2, 0, 0); ISS2_A(3, 0, 0);
#pragma unroll
  for (int r = 0; r < BR; ++r) ISS2_B(r, 0, 0);
  if (nkt > 1) {
    ISS2_A(0, 1, 64); ISS2_A(2, 1, 64);
    asm volatile("s_waitcnt vmcnt(2)" ::: "memory");
  } else {
    asm volatile("s_waitcnt vmcnt(0)" ::: "memory");
  }
  BARSB();

  auto rdA0k = [&](int buf, int m) -> bf16x8 {
    const int r = wr * 128 + m * 16 + lr;
    return *(const bf16x8*)((const char*)&Ash[buf][0] + r * 128 + (((0 + lg) ^ (r & 7)) << 4));
  };
  auto rdA1k = [&](int buf, int m) -> bf16x8 {
    const int r = wr * 128 + m * 16 + lr;
    return *(const bf16x8*)((const char*)&Ash[buf][0] + r * 128 + (((4 + lg) ^ (r & 7)) << 4));
  };
  auto rdB0k = [&](int buf, int n) -> bf16x8 {
    const int r = wc * (BR * 16) + n * 16 + lr;
    return *(const bf16x8*)((const char*)&Bsh[buf][0] + r * 128 + (((0 + lg) ^ (r & 7)) << 4));
  };
  auto rdB1k = [&](int buf, int n) -> bf16x8 {
    const int r = wc * (BR * 16) + n * 16 + lr;
    return *(const bf16x8*)((const char*)&Bsh[buf][0] + r * 128 + (((4 + lg) ^ (r & 7)) << 4));
  };

  bf16x8 afr[4][2], bfr[BR][2];

  for (int i = 0; i < nkt; ++i) {
    const int buf = i & 1, nb = buf ^ 1;
    const size_t k1 = (size_t)(i + 1) << 6, k2 = (size_t)(i + 2) << 6;
    const bool n1 = (i + 1 < nkt), n2 = (i + 2 < nkt);

    // ---- ph1: read A m0-3 + all B; issue A1,A3 + B0..B(BR-1) (t+1); MFMA (m0-3 x all n) ----
#pragma unroll
    for (int m = 0; m < 4; ++m) { afr[m][0] = rdA0k(buf, m); afr[m][1] = rdA1k(buf, m); }
#pragma unroll
    for (int n = 0; n < BR; ++n) { bfr[n][0] = rdB0k(buf, n); bfr[n][1] = rdB1k(buf, n); }
    if (n1) {
      ISS2_A(1, nb, k1); ISS2_A(3, nb, k1);
#pragma unroll
      for (int r = 0; r < BR; ++r) ISS2_B(r, nb, k1);
    }
    __builtin_amdgcn_s_setprio(1);
#pragma unroll
    for (int m = 0; m < 4; ++m)
#pragma unroll
      for (int n = 0; n < BR; ++n) {
        acc[m][n] = mfma16(afr[m][0], bfr[n][0], acc[m][n]);
        acc[m][n] = mfma16(afr[m][1], bfr[n][1], acc[m][n]);
      }
    __builtin_amdgcn_s_setprio(0);
    BARSB();

    // ---- ph2: read A m4-7; issue A0,A2(t+2); MFMA (m4-7 x all n) ----
#pragma unroll
    for (int m = 0; m < 4; ++m) { afr[m][0] = rdA0k(buf, 4 + m); afr[m][1] = rdA1k(buf, 4 + m); }
    if (n2) { ISS2_A(0, buf, k2); ISS2_A(2, buf, k2); }
    __builtin_amdgcn_s_setprio(1);
#pragma unroll
    for (int m = 0; m < 4; ++m)
#pragma unroll
      for (int n = 0; n < BR; ++n) {
        acc[4 + m][n] = mfma16(afr[m][0], bfr[n][0], acc[4 + m][n]);
        acc[4 + m][n] = mfma16(afr[m][1], bfr[n][1], acc[4 + m][n]);
      }
    __builtin_amdgcn_s_setprio(0);
    if (n1) {
      if (n2) asm volatile("s_waitcnt vmcnt(2)" ::: "memory");
      else    asm volatile("s_waitcnt vmcnt(0)" ::: "memory");
      BARSB();
    }
  }
#undef ISS2_A
#undef ISS2_B

#pragma unroll
  for (int m = 0; m < 8; ++m) {
#pragma unroll
    for (int n = 0; n < BR; ++n) {
#pragma unroll
      for (int r = 0; r < 4; ++r) {
        const int row = bm0 + wr * 128 + m * 16 + lg * 4 + r;
        const int col = bn0 + wc * (BR * 16) + n * 16 + lr;
        float v = acc[m][n][r];
        if constexpr (MODE == MODE_QKV) {
          const int sel = col >> 10, hh = (col >> 6) & 15, dh = col & 63;
          const int bi = row >> 11, tt = row & 2047;
          u16* dst = (sel == 0) ? qo : (sel == 1) ? ko : vo;
          dst[(((size_t)bi * H_ + hh) * T_ + tt) * DH_ + dh] = f2bf(v);
        } else if constexpr (MODE == MODE_MLP1) {
          v += bias[col];
          outb[(size_t)row * N + col] = f2bf(v > 0.f ? v : 0.f);
        } else if constexpr (MODE == MODE_WP) {
          v += bias[col] + bf2f(resid[(size_t)row * N + col]);
          outb[(size_t)row * N + col] = f2bf(v);
        } else if constexpr (MODE == MODE_MLP2) {
          outf[(size_t)row * N + col] = v + bias[col] + bf2f(resid[(size_t)row * N + col]);
        }
      }
    }
  }
}

// ---------------- Flash attention: paired q-tiles (qt_hi + qt_lo), KVBLK=64, 8 waves ----
// Every block does exactly 34 KV-steps -> uniform makespan. 512 blocks.
// Q pre-scaled by SC2 (removes per-step scale mul).
__global__ __launch_bounds__(512, 4)
void attn_kernel(const u16* __restrict__ q, const u16* __restrict__ k,
                 const u16* __restrict__ vt, u16* __restrict__ out)
{
  __shared__ __align__(16) u16 Ks[2][4096];   // [s=64][dh=64], chunk-swizzled (^(s&7))
  __shared__ __align__(16) u16 Vs[2][4096];   // [dh=64][s=64], chunk-swizzled (^(dh&7))
  const int t = threadIdx.x, w = t >> 6, l = t & 63, lg = l >> 4, lr = l & 15;

  const int bid = blockIdx.x;
  const int xcd = bid & 7, vv = bid >> 3;
  const int bh = xcd * 8 + (vv & 7);
  const int pair = vv >> 3;                   // 0..7

  const int b = bh >> 4, h = bh & 15;
  const u16* Qp  = q  + (size_t)bh * T_ * DH_;
  const u16* Kp  = k  + (size_t)bh * T_ * DH_;
  const u16* Vtp = vt + (size_t)bh * T_ * DH_;   // [dh][T]

  const int srow = t >> 3;
  const int schunk = ((t & 7) ^ (srow & 7)) << 3;
  const u16* Kg = Kp  + (size_t)srow * DH_ + schunk;
  const u16* Vg = Vtp + (size_t)srow * T_  + schunk;

  const float SC2 = 0.03125f * 1.44269504f;
  const float THR2 = 11.5416f;
  const size_t obase = ((size_t)b * T_) * D_ + (size_t)h * DH_;

#pragma unroll 1
  for (int pass = 0; pass < 2; ++pass) {
    const int qt = pass == 0 ? (15 - pair) : pair;   // long tile first
    const int qrow = qt * 128 + w * 16 + lr;
    bf16x8 qf0 = *(const bf16x8*)&Qp[(size_t)qrow * DH_ + lg * 8];
    bf16x8 qf1 = *(const bf16x8*)&Qp[(size_t)qrow * DH_ + 32 + lg * 8];
    {  // pre-scale Q by SC2
      union { bf16x8 v8; u16 u[8]; unsigned wd[4]; } a0, a1, r0, r1;
      a0.v8 = qf0; a1.v8 = qf1;
#pragma unroll
      for (int j = 0; j < 4; ++j) {
        unsigned pk;
        float lo = bf2f(a0.u[2 * j]) * SC2, hi = bf2f(a0.u[2 * j + 1]) * SC2;
        CVTPK(pk, lo, hi); r0.wd[j] = pk;
        lo = bf2f(a1.u[2 * j]) * SC2; hi = bf2f(a1.u[2 * j + 1]) * SC2;
        CVTPK(pk, lo, hi); r1.wd[j] = pk;
      }
      qf0 = r0.v8; qf1 = r1.v8;
    }

    float m_run = -1e30f, l_run = 0.f;
    f32x4 o[4] = {};

    GLOAD_LDS16(Kg, &Ks[0][w * 512]);
    GLOAD_LDS16(Vg, &Vs[0][w * 512]);
    __syncthreads();

    const int nst = 2 * qt + 2;
    for (int st = 0; st < nst; ++st) {
      const int cur = st & 1, nxt = cur ^ 1;
      const bool pf = (st + 1 < nst);
      if (pf) {
        GLOAD_LDS16(Kg + (size_t)(st + 1) * 64 * DH_, &Ks[nxt][w * 512]);
        GLOAD_LDS16(Vg + (size_t)(st + 1) * 64,       &Vs[nxt][w * 512]);
      }

      // S^T = K * Q^T : lane holds S[s = n*16+lg*4+r][q = lr] (Q pre-scaled)
      f32x4 sa[4] = {};
      const char* kb = (const char*)&Ks[cur][0];
      __builtin_amdgcn_s_setprio(1);
#pragma unroll
      for (int n = 0; n < 4; ++n) {
        const int sr = n * 16 + lr;
        const int base = (sr << 7) + (lg << 4);
        const int swz = (sr & 7) << 4;
        const bf16x8 b0 = *(const bf16x8*)(kb + (base ^ swz));
        const bf16x8 b1 = *(const bf16x8*)(kb + ((base + 64) ^ swz));
        sa[n] = mfma16(b0, qf0, sa[n]);
        sa[n] = mfma16(b1, qf1, sa[n]);
      }
      __builtin_amdgcn_s_setprio(0);

      if (st >= 2 * qt) {  // diagonal region (uniform branch)
#pragma unroll
        for (int n = 0; n < 4; ++n)
#pragma unroll
          for (int r = 0; r < 4; ++r)
            if (st * 64 + n * 16 + lg * 4 + r > qrow) sa[n][r] = -1e30f;
      }
      float rm = -1e30f;
#pragma unroll
      for (int n = 0; n < 4; ++n)
#pragma unroll
        for (int r = 0; r < 4; ++r)
          rm = fmaxf(rm, sa[n][r]);
      rm = fmaxf(rm, __shfl_xor(rm, 16));
      rm = fmaxf(rm, __shfl_xor(rm, 32));
      const bool noresc = __all(rm <= m_run + THR2);
      if (!noresc) {
        const float mnew = fmaxf(m_run, rm);
        const float al = exp2f(m_run - mnew);
        m_run = mnew;
        l_run *= al;
        const float alr0 = __shfl(al, lg * 4 + 0);
        const float alr1 = __shfl(al, lg * 4 + 1);
        const float alr2 = __shfl(al, lg * 4 + 2);
        const float alr3 = __shfl(al, lg * 4 + 3);
#pragma unroll
        for (int n = 0; n < 4; ++n) {
          o[n][0] *= alr0; o[n][1] *= alr1; o[n][2] *= alr2; o[n][3] *= alr3;
        }
      }
      float rs = 0.f;
#pragma unroll
      for (int n = 0; n < 4; ++n)
#pragma unroll
        for (int r = 0; r < 4; ++r) {
          sa[n][r] = exp2f(sa[n][r] - m_run);   // sa becomes P in place
          rs += sa[n][r];
        }
      rs += __shfl_xor(rs, 16);
      rs += __shfl_xor(rs, 32);
      l_run += rs;

      unsigned pk0a, pk0b, pk1a, pk1b, pk2a, pk2b, pk3a, pk3b;
      CVTPK(pk0a, sa[0][0], sa[0][1]); CVTPK(pk0b, sa[0][2], sa[0][3]);
      CVTPK(pk1a, sa[1][0], sa[1][1]); CVTPK(pk1b, sa[1][2], sa[1][3]);
      CVTPK(pk2a, sa[2][0], sa[2][1]); CVTPK(pk2b, sa[2][2], sa[2][3]);
      CVTPK(pk3a, sa[3][0], sa[3][1]); CVTPK(pk3b, sa[3][2], sa[3][3]);

      const int srcA = lr + ((l >> 4) & 1) * 32;
      const int srcB = srcA + 16;
      const bool hi = (l >> 5) & 1;
      union { uint4 u; bf16x8 v8; } f0, f1;
      {
        const unsigned xA0 = __shfl(pk0a, srcA), xA1 = __shfl(pk0b, srcA);
        const unsigned yA0 = __shfl(pk1a, srcA), yA1 = __shfl(pk1b, srcA);
        const unsigned xB0 = __shfl(pk0a, srcB), xB1 = __shfl(pk0b, srcB);
        const unsigned yB0 = __shfl(pk1a, srcB), yB1 = __shfl(pk1b, srcB);
        f0.u.x = hi ? yA0 : xA0; f0.u.y = hi ? yA1 : xA1;
        f0.u.z = hi ? yB0 : xB0; f0.u.w = hi ? yB1 : xB1;
      }
      {
        const unsigned xA0 = __shfl(pk2a, srcA), xA1 = __shfl(pk2b, srcA);
        const unsigned yA0 = __shfl(pk3a, srcA), yA1 = __shfl(pk3b, srcA);
        const unsigned xB0 = __shfl(pk2a, srcB), xB1 = __shfl(pk2b, srcB);
        const unsigned yB0 = __shfl(pk3a, srcB), yB1 = __shfl(pk3b, srcB);
        f1.u.x = hi ? yA0 : xA0; f1.u.y = hi ? yA1 : xA1;
        f1.u.z = hi ? yB0 : xB0; f1.u.w = hi ? yB1 : xB1;
      }

      // O += P * V   (V^T fragments: row = dh, chunk-swizzled)
      const char* vbase = (const char*)&Vs[cur][0];
      __builtin_amdgcn_s_setprio(1);
#pragma unroll
      for (int ks = 0; ks < 2; ++ks) {
        const bf16x8 pa = ks ? f1.v8 : f0.v8;
#pragma unroll
        for (int n = 0; n < 4; ++n) {
          const int dh = n * 16 + lr;
          const int base = (dh << 7) + (ks << 6) + (lg << 4);
          const int swz = (dh & 7) << 4;
          const bf16x8 vbf = *(const bf16x8*)(vbase + (base ^ swz));
          o[n] = mfma16(pa, vbf, o[n]);
        }
      }
      __builtin_amdgcn_s_setprio(0);

      __syncthreads();
    }

    float li[4];
    li[0] = 1.0f / __shfl(l_run, lg * 4 + 0);
    li[1] = 1.0f / __shfl(l_run, lg * 4 + 1);
    li[2] = 1.0f / __shfl(l_run, lg * 4 + 2);
    li[3] = 1.0f / __shfl(l_run, lg * 4 + 3);
#pragma unroll
    for (int n = 0; n < 4; ++n) {
#pragma unroll
      for (int r = 0; r < 4; ++r) {
        const int qg = qt * 128 + w * 16 + lg * 4 + r;
        out[obase + (size_t)qg * D_ + n * 16 + lr] = f2bf(o[n][r] * li[r]);
      }
    }
    __syncthreads();   // pass boundary: all LDS reads done before re-staging
  }
}

// ---------------- host ----------------
extern "C" void kernel_launch(void* const* d_in, const int* in_sizes, int n_in,
                              void* d_out, int out_size, void* d_ws, size_t ws_size,
                              hipStream_t stream) {
  (void)in_sizes; (void)n_in; (void)out_size; (void)ws_size;
  const float* x   = (const float*)d_in[0];
  const float* Wq  = (const float*)d_in[2];
  const float* Wk  = (const float*)d_in[3];
  const float* Wv  = (const float*)d_in[4];
  const float* Wp  = (const float*)d_in[5];
  const float* bp  = (const float*)d_in[6];
  const float* W1  = (const float*)d_in[7];
  const float* b1  = (const float*)d_in[8];
  const float* W2  = (const float*)d_in[9];
  const float* b2  = (const float*)d_in[10];
  const float* g1  = (const float*)d_in[11];
  const float* be1 = (const float*)d_in[12];
  const float* g2  = (const float*)d_in[13];
  const float* be2 = (const float*)d_in[14];

  char* ws = (char*)d_ws;
  const size_t MB16 = 16777216;
  u16* x1b   = (u16*)(ws);
  u16* qb    = (u16*)(ws + 1 * MB16);
  u16* kb    = (u16*)(ws + 2 * MB16);
  u16* vb    = (u16*)(ws + 3 * MB16);
  u16* attnb = (u16*)(ws + 4 * MB16);
  u16* x2b   = (u16*)(ws + 5 * MB16);
  u16* hb    = (u16*)(ws + 6 * MB16);
  u16* vtb   = hb;
  u16* wqkvb = (u16*)(ws + 10 * MB16);
  u16* wpb   = (u16*)(ws + 10 * MB16 + 6291456);
  u16* w1b   = (u16*)(ws + 10 * MB16 + 8388608);
  u16* w2b   = (u16*)(ws + 11 * MB16);
  u16* x3b   = qb;

  dim3 tb(32, 8, 1);
  transpose_cvt3<<<dim3(2, 32, 48),  tb, 0, stream>>>(Wq, Wk, Wv, wqkvb);
  transpose_cvt<<<dim3(32, 32, 1),  tb, 0, stream>>>(Wp, wpb, 1024, 1024);
  transpose_cvt<<<dim3(128, 32, 1), tb, 0, stream>>>(W1, w1b, 1024, 4096);
  transpose_cvt<<<dim3(32, 128, 1), tb, 0, stream>>>(W2, w2b, 4096, 1024);

  ln_kernel<float><<<8192, 256, 0, stream>>>(x, g1, be1, x1b);

  gemm256v3<MODE_QKV, 4><<<dim3(12, 32), 512, 0, stream>>>(
      x1b, wqkvb, 8192, 3072, 1024, nullptr, nullptr, nullptr, nullptr, qb, kb, vb);

  transpose_bf<<<dim3(2, 64, 64), tb, 0, stream>>>(vb, vtb, 2048, 64);

  attn_kernel<<<dim3(512), 512, 0, stream>>>(qb, kb, vtb, attnb);

  gemm256v3<MODE_WP, 2><<<dim3(8, 32), 512, 0, stream>>>(
      attnb, wpb, 8192, 1024, 1024, bp, x1b, nullptr, x2b, nullptr, nullptr, nullptr);

  ln_kernel<u16><<<8192, 256, 0, stream>>>(x2b, g2, be2, x3b);

  gemm256v3<MODE_MLP1, 4><<<dim3(16, 32), 512, 0, stream>>>(
      x3b, w1b, 8192, 4096, 1024, b1, nullptr, nullptr, hb, nullptr, nullptr, nullptr);

  gemm256v3<MODE_MLP2, 2><<<dim3(8, 32), 512, 0, stream>>>(
      hb, w2b, 8192, 1024, 4096, b2, x3b, (float*)d_out, nullptr, nullptr, nullptr, nullptr);
}

// Round 16
// 351.934 us; speedup vs baseline: 1.0138x; 1.0138x over previous
//
#include <hip/hip_runtime.h>

// Transformer block forward, MI355X gfx950.
// B=4, T=2048, D=1024, H=16, DH=64. bf16 MFMA compute, bf16 intermediates.

#define B_ 4
#define T_ 2048
#define D_ 1024
#define H_ 16
#define DH_ 64

using u16 = unsigned short;
typedef short bf16x8 __attribute__((ext_vector_type(8)));   // 8 bf16 (4 VGPRs)
typedef float f32x4 __attribute__((ext_vector_type(4)));

#define GLOAD_LDS16(g, l)                                                          \
  __builtin_amdgcn_global_load_lds((const __attribute__((address_space(1))) void*)(g), \
                                   (__attribute__((address_space(3))) void*)(l), 16, 0, 0)

#define CVTPK(d, lo, hi) asm("v_cvt_pk_bf16_f32 %0, %1, %2" : "=v"(d) : "v"(lo), "v"(hi))
#define BARSB() do { __builtin_amdgcn_s_barrier(); __builtin_amdgcn_sched_barrier(0); } while (0)

__device__ __forceinline__ f32x4 mfma16(bf16x8 a, bf16x8 b, f32x4 c) {
  return __builtin_amdgcn_mfma_f32_16x16x32_bf16(a, b, c, 0, 0, 0);
}

__device__ __forceinline__ u16 f2bf(float f) {  // RNE f32->bf16
  union { float f; unsigned u; } v; v.f = f;
  unsigned r = v.u + 0x7fffu + ((v.u >> 16) & 1u);
  return (u16)(r >> 16);
}
__device__ __forceinline__ float bf2f(u16 h) {
  union { unsigned u; float f; } v; v.u = ((unsigned)h) << 16; return v.f;
}

// ---------------- LayerNorm: x[row][1024] (f32 or bf16) -> bf16 ----------------
template<typename TI>
__global__ __launch_bounds__(256)
void ln_kernel(const TI* __restrict__ x, const float* __restrict__ g,
               const float* __restrict__ be, u16* __restrict__ yb)
{
  const int row = blockIdx.x;
  const int tid = threadIdx.x;
  float v0, v1, v2, v3;
  if constexpr (sizeof(TI) == 4) {
    const float4 vx = ((const float4*)(x + (size_t)row * D_))[tid];
    v0 = vx.x; v1 = vx.y; v2 = vx.z; v3 = vx.w;
  } else {
    const ushort4 vx = ((const ushort4*)((const u16*)x + (size_t)row * D_))[tid];
    v0 = bf2f(vx.x); v1 = bf2f(vx.y); v2 = bf2f(vx.z); v3 = bf2f(vx.w);
  }
  float s  = v0 + v1 + v2 + v3;
  float s2 = v0*v0 + v1*v1 + v2*v2 + v3*v3;
#pragma unroll
  for (int m = 1; m < 64; m <<= 1) { s += __shfl_xor(s, m); s2 += __shfl_xor(s2, m); }
  __shared__ float red[8];
  const int w = tid >> 6;
  if ((tid & 63) == 0) { red[w] = s; red[4 + w] = s2; }
  __syncthreads();
  s  = red[0] + red[1] + red[2] + red[3];
  s2 = red[4] + red[5] + red[6] + red[7];
  const float mu   = s * (1.0f / D_);
  const float rstd = rsqrtf(s2 * (1.0f / D_) - mu * mu + 1e-5f);
  const float4 gg = ((const float4*)g)[tid];
  const float4 bb = ((const float4*)be)[tid];
  ushort4 pk;
  pk.x = f2bf((v0 - mu) * rstd * gg.x + bb.x);
  pk.y = f2bf((v1 - mu) * rstd * gg.y + bb.y);
  pk.z = f2bf((v2 - mu) * rstd * gg.z + bb.z);
  pk.w = f2bf((v3 - mu) * rstd * gg.w + bb.w);
  ((ushort4*)(yb + (size_t)row * D_))[tid] = pk;
}

// ------------- transpose + cvt: in f32 [R][C] -> out bf16 [C][R], per z-matrix -------------
__global__ __launch_bounds__(256)
void transpose_cvt(const float* __restrict__ in, u16* __restrict__ out, int R, int C)
{
  __shared__ float tile[32][33];
  const int c0 = blockIdx.x * 32, r0 = blockIdx.y * 32;
  const float* ip = in + (size_t)blockIdx.z * R * C;
  u16* op = out + (size_t)blockIdx.z * R * C;
  const int tx = threadIdx.x, ty = threadIdx.y;  // 32 x 8
#pragma unroll
  for (int j = 0; j < 4; ++j)
    tile[ty + j * 8][tx] = ip[(size_t)(r0 + ty + j * 8) * C + (c0 + tx)];
  __syncthreads();
#pragma unroll
  for (int j = 0; j < 4; ++j)
    op[(size_t)(c0 + ty + j * 8) * R + (r0 + tx)] = f2bf(tile[tx][ty + j * 8]);
}

// ------------- fused Wq/Wk/Wv transpose (R=1024, C=64; z = mat*16 + zz) -------------
__global__ __launch_bounds__(256)
void transpose_cvt3(const float* __restrict__ w0, const float* __restrict__ w1,
                    const float* __restrict__ w2, u16* __restrict__ out)
{
  __shared__ float tile[32][33];
  const int R = 1024, C = 64;
  const int mat = blockIdx.z >> 4, zz = blockIdx.z & 15;
  const float* in = (mat == 0) ? w0 : (mat == 1) ? w1 : w2;
  const int c0 = blockIdx.x * 32, r0 = blockIdx.y * 32;
  const float* ip = in + (size_t)zz * R * C;
  u16* op = out + (size_t)mat * 1048576 + (size_t)zz * R * C;
  const int tx = threadIdx.x, ty = threadIdx.y;
#pragma unroll
  for (int j = 0; j < 4; ++j)
    tile[ty + j * 8][tx] = ip[(size_t)(r0 + ty + j * 8) * C + (c0 + tx)];
  __syncthreads();
#pragma unroll
  for (int j = 0; j < 4; ++j)
    op[(size_t)(c0 + ty + j * 8) * R + (r0 + tx)] = f2bf(tile[tx][ty + j * 8]);
}

#define MODE_QKV 0
#define MODE_WP 1
#define MODE_MLP1 2
#define MODE_MLP2 3
#define MODE_VT 4

// ---------------- gemm256v3: BM=256, BN=BR*64, BK=64, 8 waves, 2 phases/K-tile ----------
// Ledger (loads/tile = 4+BR): entering tile i in-flight = A0,A2(t+1) [2];
// ph1 +(2+BR); ph2 +2; tile-end vmcnt(2) confirms all of t+1, leaves A0,A2(t+2).
// Never drains mid-loop. ph2's A0,A2(t+2) overwrite rows read only in ph1 (barrier-safe).
template<int MODE, int BR>
__global__ __launch_bounds__(512, 2)
void gemm256v3(const u16* __restrict__ A, const u16* __restrict__ Bt,
               int M, int N, int K,
               const float* __restrict__ bias, const u16* __restrict__ resid,
               float* __restrict__ outf, u16* __restrict__ outb,
               u16* __restrict__ qo, u16* __restrict__ ko, u16* __restrict__ vo)
{
  __shared__ __align__(16) u16 Ash[2][256 * 64];
  __shared__ __align__(16) u16 Bsh[2][BR * 64 * 64];
  const int t = threadIdx.x, w = t >> 6, l = t & 63, lg = l >> 4, lr = l & 15;
  const int wr = w >> 2, wc = w & 3;

  const int gx = gridDim.x;
  const int nwg = gx * gridDim.y;
  const int bid = blockIdx.y * gx + blockIdx.x;
  const int cpx = nwg >> 3;
  const int virt = (bid & 7) * cpx + (bid >> 3);
  const int bn0 = (virt % gx) * (BR * 64), bm0 = (virt / gx) * 256;

  f32x4 acc[8][BR] = {};

  const int srow = t >> 3;
  const int sc16 = (t & 7) ^ (srow & 7);
  const u16* gAs = A  + (size_t)(bm0 + srow) * K + sc16 * 8;
  const u16* gBs = Bt + (size_t)(bn0 + srow) * K + sc16 * 8;

#define ISS2_A(R, BUF, ko) GLOAD_LDS16(gAs + (size_t)(R) * 64 * K + (ko), &Ash[BUF][(R) * 4096 + w * 512])
#define ISS2_B(R, BUF, ko) GLOAD_LDS16(gBs + (size_t)(R) * 64 * K + (ko), &Bsh[BUF][(R) * 4096 + w * 512])

  const int nkt = K >> 6;
  ISS2_A(0, 0, 0); ISS2_A(1, 0, 0); ISS2_A(2, 0, 0); ISS2_A(3, 0, 0);
#pragma unroll
  for (int r = 0; r < BR; ++r) ISS2_B(r, 0, 0);
  if (nkt > 1) {
    ISS2_A(0, 1, 64); ISS2_A(2, 1, 64);
    asm volatile("s_waitcnt vmcnt(2)" ::: "memory");
  } else {
    asm volatile("s_waitcnt vmcnt(0)" ::: "memory");
  }
  BARSB();

  auto rdA0k = [&](int buf, int m) -> bf16x8 {
    const int r = wr * 128 + m * 16 + lr;
    return *(const bf16x8*)((const char*)&Ash[buf][0] + r * 128 + (((0 + lg) ^ (r & 7)) << 4));
  };
  auto rdA1k = [&](int buf, int m) -> bf16x8 {
    const int r = wr * 128 + m * 16 + lr;
    return *(const bf16x8*)((const char*)&Ash[buf][0] + r * 128 + (((4 + lg) ^ (r & 7)) << 4));
  };
  auto rdB0k = [&](int buf, int n) -> bf16x8 {
    const int r = wc * (BR * 16) + n * 16 + lr;
    return *(const bf16x8*)((const char*)&Bsh[buf][0] + r * 128 + (((0 + lg) ^ (r & 7)) << 4));
  };
  auto rdB1k = [&](int buf, int n) -> bf16x8 {
    const int r = wc * (BR * 16) + n * 16 + lr;
    return *(const bf16x8*)((const char*)&Bsh[buf][0] + r * 128 + (((4 + lg) ^ (r & 7)) << 4));
  };

  bf16x8 afr[4][2], bfr[BR][2];

  for (int i = 0; i < nkt; ++i) {
    const int buf = i & 1, nb = buf ^ 1;
    const size_t k1 = (size_t)(i + 1) << 6, k2 = (size_t)(i + 2) << 6;
    const bool n1 = (i + 1 < nkt), n2 = (i + 2 < nkt);

    // ---- ph1: read A m0-3 + all B; issue A1,A3 + B0..B(BR-1) (t+1); MFMA (m0-3 x all n) ----
#pragma unroll
    for (int m = 0; m < 4; ++m) { afr[m][0] = rdA0k(buf, m); afr[m][1] = rdA1k(buf, m); }
#pragma unroll
    for (int n = 0; n < BR; ++n) { bfr[n][0] = rdB0k(buf, n); bfr[n][1] = rdB1k(buf, n); }
    if (n1) {
      ISS2_A(1, nb, k1); ISS2_A(3, nb, k1);
#pragma unroll
      for (int r = 0; r < BR; ++r) ISS2_B(r, nb, k1);
    }
    __builtin_amdgcn_s_setprio(1);
#pragma unroll
    for (int m = 0; m < 4; ++m)
#pragma unroll
      for (int n = 0; n < BR; ++n) {
        acc[m][n] = mfma16(afr[m][0], bfr[n][0], acc[m][n]);
        acc[m][n] = mfma16(afr[m][1], bfr[n][1], acc[m][n]);
      }
    __builtin_amdgcn_s_setprio(0);
    BARSB();

    // ---- ph2: read A m4-7; issue A0,A2(t+2); MFMA (m4-7 x all n) ----
#pragma unroll
    for (int m = 0; m < 4; ++m) { afr[m][0] = rdA0k(buf, 4 + m); afr[m][1] = rdA1k(buf, 4 + m); }
    if (n2) { ISS2_A(0, buf, k2); ISS2_A(2, buf, k2); }
    __builtin_amdgcn_s_setprio(1);
#pragma unroll
    for (int m = 0; m < 4; ++m)
#pragma unroll
      for (int n = 0; n < BR; ++n) {
        acc[4 + m][n] = mfma16(afr[m][0], bfr[n][0], acc[4 + m][n]);
        acc[4 + m][n] = mfma16(afr[m][1], bfr[n][1], acc[4 + m][n]);
      }
    __builtin_amdgcn_s_setprio(0);
    if (n1) {
      if (n2) asm volatile("s_waitcnt vmcnt(2)" ::: "memory");
      else    asm volatile("s_waitcnt vmcnt(0)" ::: "memory");
      BARSB();
    }
  }
#undef ISS2_A
#undef ISS2_B

#pragma unroll
  for (int m = 0; m < 8; ++m) {
#pragma unroll
    for (int n = 0; n < BR; ++n) {
#pragma unroll
      for (int r = 0; r < 4; ++r) {
        const int row = bm0 + wr * 128 + m * 16 + lg * 4 + r;
        const int col = bn0 + wc * (BR * 16) + n * 16 + lr;
        float v = acc[m][n][r];
        if constexpr (MODE == MODE_QKV) {   // N=2048: Q,K only
          const int sel = col >> 10, hh = (col >> 6) & 15, dh = col & 63;
          const int bi = row >> 11, tt = row & 2047;
          u16* dst = (sel == 0) ? qo : ko;
          dst[(((size_t)bi * H_ + hh) * T_ + tt) * DH_ + dh] = f2bf(v);
        } else if constexpr (MODE == MODE_VT) {  // C[dh_glob][t_glob] -> vtb[bh][dh][T]
          const int hh = row >> 6, dh = row & 63;
          const int bi = col >> 11, tt = col & 2047;
          outb[(((size_t)bi * H_ + hh) * DH_ + dh) * T_ + tt] = f2bf(v);
        } else if constexpr (MODE == MODE_MLP1) {
          v += bias[col];
          outb[(size_t)row * N + col] = f2bf(v > 0.f ? v : 0.f);
        } else if constexpr (MODE == MODE_WP) {
          v += bias[col] + bf2f(resid[(size_t)row * N + col]);
          outb[(size_t)row * N + col] = f2bf(v);
        } else if constexpr (MODE == MODE_MLP2) {
          outf[(size_t)row * N + col] = v + bias[col] + bf2f(resid[(size_t)row * N + col]);
        }
      }
    }
  }
}

// ---------------- Flash attention: paired q-tiles (qt_hi + qt_lo), KVBLK=64, 8 waves ----
// Every block does exactly 34 KV-steps -> uniform makespan. 512 blocks.
__global__ __launch_bounds__(512, 4)
void attn_kernel(const u16* __restrict__ q, const u16* __restrict__ k,
                 const u16* __restrict__ vt, u16* __restrict__ out)
{
  __shared__ __align__(16) u16 Ks[2][4096];   // [s=64][dh=64], chunk-swizzled (^(s&7))
  __shared__ __align__(16) u16 Vs[2][4096];   // [dh=64][s=64], chunk-swizzled (^(dh&7))
  const int t = threadIdx.x, w = t >> 6, l = t & 63, lg = l >> 4, lr = l & 15;

  const int bid = blockIdx.x;
  const int xcd = bid & 7, vv = bid >> 3;
  const int bh = xcd * 8 + (vv & 7);
  const int pair = vv >> 3;                   // 0..7

  const int b = bh >> 4, h = bh & 15;
  const u16* Qp  = q  + (size_t)bh * T_ * DH_;
  const u16* Kp  = k  + (size_t)bh * T_ * DH_;
  const u16* Vtp = vt + (size_t)bh * T_ * DH_;   // [dh][T]

  const int srow = t >> 3;
  const int schunk = ((t & 7) ^ (srow & 7)) << 3;
  const u16* Kg = Kp  + (size_t)srow * DH_ + schunk;
  const u16* Vg = Vtp + (size_t)srow * T_  + schunk;

  const float SC2 = 0.03125f * 1.44269504f;
  const float THR2 = 11.5416f;
  const size_t obase = ((size_t)b * T_) * D_ + (size_t)h * DH_;

#pragma unroll 1
  for (int pass = 0; pass < 2; ++pass) {
    const int qt = pass == 0 ? (15 - pair) : pair;   // long tile first
    const int qrow = qt * 128 + w * 16 + lr;
    bf16x8 qf0 = *(const bf16x8*)&Qp[(size_t)qrow * DH_ + lg * 8];
    bf16x8 qf1 = *(const bf16x8*)&Qp[(size_t)qrow * DH_ + 32 + lg * 8];
    {  // pre-scale Q by SC2
      union { bf16x8 v8; u16 u[8]; unsigned wd[4]; } a0, a1, r0, r1;
      a0.v8 = qf0; a1.v8 = qf1;
#pragma unroll
      for (int j = 0; j < 4; ++j) {
        unsigned pk;
        float lo = bf2f(a0.u[2 * j]) * SC2, hi = bf2f(a0.u[2 * j + 1]) * SC2;
        CVTPK(pk, lo, hi); r0.wd[j] = pk;
        lo = bf2f(a1.u[2 * j]) * SC2; hi = bf2f(a1.u[2 * j + 1]) * SC2;
        CVTPK(pk, lo, hi); r1.wd[j] = pk;
      }
      qf0 = r0.v8; qf1 = r1.v8;
    }

    float m_run = -1e30f, l_run = 0.f;
    f32x4 o[4] = {};

    GLOAD_LDS16(Kg, &Ks[0][w * 512]);
    GLOAD_LDS16(Vg, &Vs[0][w * 512]);
    __syncthreads();

    const int nst = 2 * qt + 2;
    for (int st = 0; st < nst; ++st) {
      const int cur = st & 1, nxt = cur ^ 1;
      const bool pf = (st + 1 < nst);
      if (pf) {
        GLOAD_LDS16(Kg + (size_t)(st + 1) * 64 * DH_, &Ks[nxt][w * 512]);
        GLOAD_LDS16(Vg + (size_t)(st + 1) * 64,       &Vs[nxt][w * 512]);
      }

      // S^T = K * Q^T : lane holds S[s = n*16+lg*4+r][q = lr] (Q pre-scaled)
      f32x4 sa[4] = {};
      const char* kb = (const char*)&Ks[cur][0];
      __builtin_amdgcn_s_setprio(1);
#pragma unroll
      for (int n = 0; n < 4; ++n) {
        const int sr = n * 16 + lr;
        const int base = (sr << 7) + (lg << 4);
        const int swz = (sr & 7) << 4;
        const bf16x8 b0 = *(const bf16x8*)(kb + (base ^ swz));
        const bf16x8 b1 = *(const bf16x8*)(kb + ((base + 64) ^ swz));
        sa[n] = mfma16(b0, qf0, sa[n]);
        sa[n] = mfma16(b1, qf1, sa[n]);
      }
      __builtin_amdgcn_s_setprio(0);

      if (st >= 2 * qt) {  // diagonal region (uniform branch)
#pragma unroll
        for (int n = 0; n < 4; ++n)
#pragma unroll
          for (int r = 0; r < 4; ++r)
            if (st * 64 + n * 16 + lg * 4 + r > qrow) sa[n][r] = -1e30f;
      }
      float rm = -1e30f;
#pragma unroll
      for (int n = 0; n < 4; ++n)
#pragma unroll
        for (int r = 0; r < 4; ++r)
          rm = fmaxf(rm, sa[n][r]);
      rm = fmaxf(rm, __shfl_xor(rm, 16));
      rm = fmaxf(rm, __shfl_xor(rm, 32));
      const bool noresc = __all(rm <= m_run + THR2);
      if (!noresc) {
        const float mnew = fmaxf(m_run, rm);
        const float al = exp2f(m_run - mnew);
        m_run = mnew;
        l_run *= al;
        const float alr0 = __shfl(al, lg * 4 + 0);
        const float alr1 = __shfl(al, lg * 4 + 1);
        const float alr2 = __shfl(al, lg * 4 + 2);
        const float alr3 = __shfl(al, lg * 4 + 3);
#pragma unroll
        for (int n = 0; n < 4; ++n) {
          o[n][0] *= alr0; o[n][1] *= alr1; o[n][2] *= alr2; o[n][3] *= alr3;
        }
      }
      float rs = 0.f;
#pragma unroll
      for (int n = 0; n < 4; ++n)
#pragma unroll
        for (int r = 0; r < 4; ++r) {
          sa[n][r] = exp2f(sa[n][r] - m_run);   // sa becomes P in place
          rs += sa[n][r];
        }
      rs += __shfl_xor(rs, 16);
      rs += __shfl_xor(rs, 32);
      l_run += rs;

      unsigned pk0a, pk0b, pk1a, pk1b, pk2a, pk2b, pk3a, pk3b;
      CVTPK(pk0a, sa[0][0], sa[0][1]); CVTPK(pk0b, sa[0][2], sa[0][3]);
      CVTPK(pk1a, sa[1][0], sa[1][1]); CVTPK(pk1b, sa[1][2], sa[1][3]);
      CVTPK(pk2a, sa[2][0], sa[2][1]); CVTPK(pk2b, sa[2][2], sa[2][3]);
      CVTPK(pk3a, sa[3][0], sa[3][1]); CVTPK(pk3b, sa[3][2], sa[3][3]);

      const int srcA = lr + ((l >> 4) & 1) * 32;
      const int srcB = srcA + 16;
      const bool hi = (l >> 5) & 1;
      union { uint4 u; bf16x8 v8; } f0, f1;
      {
        const unsigned xA0 = __shfl(pk0a, srcA), xA1 = __shfl(pk0b, srcA);
        const unsigned yA0 = __shfl(pk1a, srcA), yA1 = __shfl(pk1b, srcA);
        const unsigned xB0 = __shfl(pk0a, srcB), xB1 = __shfl(pk0b, srcB);
        const unsigned yB0 = __shfl(pk1a, srcB), yB1 = __shfl(pk1b, srcB);
        f0.u.x = hi ? yA0 : xA0; f0.u.y = hi ? yA1 : xA1;
        f0.u.z = hi ? yB0 : xB0; f0.u.w = hi ? yB1 : xB1;
      }
      {
        const unsigned xA0 = __shfl(pk2a, srcA), xA1 = __shfl(pk2b, srcA);
        const unsigned yA0 = __shfl(pk3a, srcA), yA1 = __shfl(pk3b, srcA);
        const unsigned xB0 = __shfl(pk2a, srcB), xB1 = __shfl(pk2b, srcB);
        const unsigned yB0 = __shfl(pk3a, srcB), yB1 = __shfl(pk3b, srcB);
        f1.u.x = hi ? yA0 : xA0; f1.u.y = hi ? yA1 : xA1;
        f1.u.z = hi ? yB0 : xB0; f1.u.w = hi ? yB1 : xB1;
      }

      // O += P * V   (V^T fragments: row = dh, chunk-swizzled)
      const char* vbase = (const char*)&Vs[cur][0];
      __builtin_amdgcn_s_setprio(1);
#pragma unroll
      for (int ks = 0; ks < 2; ++ks) {
        const bf16x8 pa = ks ? f1.v8 : f0.v8;
#pragma unroll
        for (int n = 0; n < 4; ++n) {
          const int dh = n * 16 + lr;
          const int base = (dh << 7) + (ks << 6) + (lg << 4);
          const int swz = (dh & 7) << 4;
          const bf16x8 vbf = *(const bf16x8*)(vbase + (base ^ swz));
          o[n] = mfma16(pa, vbf, o[n]);
        }
      }
      __builtin_amdgcn_s_setprio(0);

      __syncthreads();
    }

    float li[4];
    li[0] = 1.0f / __shfl(l_run, lg * 4 + 0);
    li[1] = 1.0f / __shfl(l_run, lg * 4 + 1);
    li[2] = 1.0f / __shfl(l_run, lg * 4 + 2);
    li[3] = 1.0f / __shfl(l_run, lg * 4 + 3);
#pragma unroll
    for (int n = 0; n < 4; ++n) {
#pragma unroll
      for (int r = 0; r < 4; ++r) {
        const int qg = qt * 128 + w * 16 + lg * 4 + r;
        out[obase + (size_t)qg * D_ + n * 16 + lr] = f2bf(o[n][r] * li[r]);
      }
    }
    __syncthreads();   // pass boundary: all LDS reads done before re-staging
  }
}

// ---------------- host ----------------
extern "C" void kernel_launch(void* const* d_in, const int* in_sizes, int n_in,
                              void* d_out, int out_size, void* d_ws, size_t ws_size,
                              hipStream_t stream) {
  (void)in_sizes; (void)n_in; (void)out_size; (void)ws_size;
  const float* x   = (const float*)d_in[0];
  const float* Wq  = (const float*)d_in[2];
  const float* Wk  = (const float*)d_in[3];
  const float* Wv  = (const float*)d_in[4];
  const float* Wp  = (const float*)d_in[5];
  const float* bp  = (const float*)d_in[6];
  const float* W1  = (const float*)d_in[7];
  const float* b1  = (const float*)d_in[8];
  const float* W2  = (const float*)d_in[9];
  const float* b2  = (const float*)d_in[10];
  const float* g1  = (const float*)d_in[11];
  const float* be1 = (const float*)d_in[12];
  const float* g2  = (const float*)d_in[13];
  const float* be2 = (const float*)d_in[14];

  char* ws = (char*)d_ws;
  const size_t MB16 = 16777216;
  u16* x1b   = (u16*)(ws);
  u16* qb    = (u16*)(ws + 1 * MB16);
  u16* kb    = (u16*)(ws + 2 * MB16);
  u16* attnb = (u16*)(ws + 4 * MB16);
  u16* x2b   = (u16*)(ws + 5 * MB16);
  u16* hb    = (u16*)(ws + 6 * MB16);
  u16* vtb   = (u16*)(ws + 3 * MB16);      // V^T [bh][64][2048], own buffer
  u16* wqkvb = (u16*)(ws + 10 * MB16);
  u16* wpb   = (u16*)(ws + 10 * MB16 + 6291456);
  u16* w1b   = (u16*)(ws + 10 * MB16 + 8388608);
  u16* w2b   = (u16*)(ws + 11 * MB16);
  u16* x3b   = qb;

  dim3 tb(32, 8, 1);
  transpose_cvt3<<<dim3(2, 32, 48),  tb, 0, stream>>>(Wq, Wk, Wv, wqkvb);
  transpose_cvt<<<dim3(32, 32, 1),  tb, 0, stream>>>(Wp, wpb, 1024, 1024);
  transpose_cvt<<<dim3(128, 32, 1), tb, 0, stream>>>(W1, w1b, 1024, 4096);
  transpose_cvt<<<dim3(32, 128, 1), tb, 0, stream>>>(W2, w2b, 4096, 1024);

  ln_kernel<float><<<8192, 256, 0, stream>>>(x, g1, be1, x1b);

  // Q,K: C[8192 t][2048 qk] — 256 blocks = 1 perfect round
  gemm256v3<MODE_QKV, 4><<<dim3(8, 32), 512, 0, stream>>>(
      x1b, wqkvb, 8192, 2048, 1024, nullptr, nullptr, nullptr, nullptr, qb, kb, nullptr);

  // V^T directly: A = Wv^T [1024 dh][1024 k], Bt = x1b [8192 t][1024 k]
  gemm256v3<MODE_VT, 4><<<dim3(32, 4), 512, 0, stream>>>(
      wqkvb + (size_t)2097152, x1b, 1024, 8192, 1024,
      nullptr, nullptr, nullptr, vtb, nullptr, nullptr, nullptr);

  attn_kernel<<<dim3(512), 512, 0, stream>>>(qb, kb, vtb, attnb);

  gemm256v3<MODE_WP, 2><<<dim3(8, 32), 512, 0, stream>>>(
      attnb, wpb, 8192, 1024, 1024, bp, x1b, nullptr, x2b, nullptr, nullptr, nullptr);

  ln_kernel<u16><<<8192, 256, 0, stream>>>(x2b, g2, be2, x3b);

  gemm256v3<MODE_MLP1, 4><<<dim3(16, 32), 512, 0, stream>>>(
      x3b, w1b, 8192, 4096, 1024, b1, nullptr, nullptr, hb, nullptr, nullptr, nullptr);

  gemm256v3<MODE_MLP2, 2><<<dim3(8, 32), 512, 0, stream>>>(
      hb, w2b, 8192, 1024, 4096, b2, x3b, (float*)d_out, nullptr, nullptr, nullptr, nullptr);
}

// Round 17
// 344.237 us; speedup vs baseline: 1.0364x; 1.0224x over previous
//
#include <hip/hip_runtime.h>

// Transformer block forward, MI355X gfx950.
// B=4, T=2048, D=1024, H=16, DH=64. bf16 MFMA compute, bf16 intermediates.

#define B_ 4
#define T_ 2048
#define D_ 1024
#define H_ 16
#define DH_ 64

using u16 = unsigned short;
typedef short bf16x8 __attribute__((ext_vector_type(8)));   // 8 bf16 (4 VGPRs)
typedef float f32x4 __attribute__((ext_vector_type(4)));

#define GLOAD_LDS16(g, l)                                                          \
  __builtin_amdgcn_global_load_lds((const __attribute__((address_space(1))) void*)(g), \
                                   (__attribute__((address_space(3))) void*)(l), 16, 0, 0)

#define CVTPK(d, lo, hi) asm("v_cvt_pk_bf16_f32 %0, %1, %2" : "=v"(d) : "v"(lo), "v"(hi))
#define BARSB() do { __builtin_amdgcn_s_barrier(); __builtin_amdgcn_sched_barrier(0); } while (0)

__device__ __forceinline__ f32x4 mfma16(bf16x8 a, bf16x8 b, f32x4 c) {
  return __builtin_amdgcn_mfma_f32_16x16x32_bf16(a, b, c, 0, 0, 0);
}

__device__ __forceinline__ u16 f2bf(float f) {  // RNE f32->bf16
  union { float f; unsigned u; } v; v.f = f;
  unsigned r = v.u + 0x7fffu + ((v.u >> 16) & 1u);
  return (u16)(r >> 16);
}
__device__ __forceinline__ float bf2f(u16 h) {
  union { unsigned u; float f; } v; v.u = ((unsigned)h) << 16; return v.f;
}

// ---------------- LayerNorm: x[row][1024] (f32 or bf16) -> bf16 ----------------
template<typename TI>
__global__ __launch_bounds__(256)
void ln_kernel(const TI* __restrict__ x, const float* __restrict__ g,
               const float* __restrict__ be, u16* __restrict__ yb)
{
  const int row = blockIdx.x;
  const int tid = threadIdx.x;
  float v0, v1, v2, v3;
  if constexpr (sizeof(TI) == 4) {
    const float4 vx = ((const float4*)(x + (size_t)row * D_))[tid];
    v0 = vx.x; v1 = vx.y; v2 = vx.z; v3 = vx.w;
  } else {
    const ushort4 vx = ((const ushort4*)((const u16*)x + (size_t)row * D_))[tid];
    v0 = bf2f(vx.x); v1 = bf2f(vx.y); v2 = bf2f(vx.z); v3 = bf2f(vx.w);
  }
  float s  = v0 + v1 + v2 + v3;
  float s2 = v0*v0 + v1*v1 + v2*v2 + v3*v3;
#pragma unroll
  for (int m = 1; m < 64; m <<= 1) { s += __shfl_xor(s, m); s2 += __shfl_xor(s2, m); }
  __shared__ float red[8];
  const int w = tid >> 6;
  if ((tid & 63) == 0) { red[w] = s; red[4 + w] = s2; }
  __syncthreads();
  s  = red[0] + red[1] + red[2] + red[3];
  s2 = red[4] + red[5] + red[6] + red[7];
  const float mu   = s * (1.0f / D_);
  const float rstd = rsqrtf(s2 * (1.0f / D_) - mu * mu + 1e-5f);
  const float4 gg = ((const float4*)g)[tid];
  const float4 bb = ((const float4*)be)[tid];
  ushort4 pk;
  pk.x = f2bf((v0 - mu) * rstd * gg.x + bb.x);
  pk.y = f2bf((v1 - mu) * rstd * gg.y + bb.y);
  pk.z = f2bf((v2 - mu) * rstd * gg.z + bb.z);
  pk.w = f2bf((v3 - mu) * rstd * gg.w + bb.w);
  ((ushort4*)(yb + (size_t)row * D_))[tid] = pk;
}

// ------------- transpose + cvt: in f32 [R][C] -> out bf16 [C][R], per z-matrix -------------
__global__ __launch_bounds__(256)
void transpose_cvt(const float* __restrict__ in, u16* __restrict__ out, int R, int C)
{
  __shared__ float tile[32][33];
  const int c0 = blockIdx.x * 32, r0 = blockIdx.y * 32;
  const float* ip = in + (size_t)blockIdx.z * R * C;
  u16* op = out + (size_t)blockIdx.z * R * C;
  const int tx = threadIdx.x, ty = threadIdx.y;  // 32 x 8
#pragma unroll
  for (int j = 0; j < 4; ++j)
    tile[ty + j * 8][tx] = ip[(size_t)(r0 + ty + j * 8) * C + (c0 + tx)];
  __syncthreads();
#pragma unroll
  for (int j = 0; j < 4; ++j)
    op[(size_t)(c0 + ty + j * 8) * R + (r0 + tx)] = f2bf(tile[tx][ty + j * 8]);
}

// ------------- fused Wq/Wk/Wv transpose (R=1024, C=64; z = mat*16 + zz) -------------
__global__ __launch_bounds__(256)
void transpose_cvt3(const float* __restrict__ w0, const float* __restrict__ w1,
                    const float* __restrict__ w2, u16* __restrict__ out)
{
  __shared__ float tile[32][33];
  const int R = 1024, C = 64;
  const int mat = blockIdx.z >> 4, zz = blockIdx.z & 15;
  const float* in = (mat == 0) ? w0 : (mat == 1) ? w1 : w2;
  const int c0 = blockIdx.x * 32, r0 = blockIdx.y * 32;
  const float* ip = in + (size_t)zz * R * C;
  u16* op = out + (size_t)mat * 1048576 + (size_t)zz * R * C;
  const int tx = threadIdx.x, ty = threadIdx.y;
#pragma unroll
  for (int j = 0; j < 4; ++j)
    tile[ty + j * 8][tx] = ip[(size_t)(r0 + ty + j * 8) * C + (c0 + tx)];
  __syncthreads();
#pragma unroll
  for (int j = 0; j < 4; ++j)
    op[(size_t)(c0 + ty + j * 8) * R + (r0 + tx)] = f2bf(tile[tx][ty + j * 8]);
}

#define MODE_QKV 0
#define MODE_WP 1
#define MODE_MLP1 2
#define MODE_MLP2 3
#define MODE_VT 4

// ---------------- gemm256v3: BM=256, BN=BR*64, BK=64, 8 waves, 2 phases/K-tile ----------
// Ledger (loads/tile = 4+BR): entering tile i in-flight = A0,A2(t+1) [2];
// ph1 +(2+BR); ph2 +2; tile-end vmcnt(2) confirms all of t+1, leaves A0,A2(t+2).
// Never drains mid-loop. ph2's A0,A2(t+2) overwrite rows read only in ph1 (barrier-safe).
template<int MODE, int BR>
__global__ __launch_bounds__(512, 2)
void gemm256v3(const u16* __restrict__ A, const u16* __restrict__ Bt,
               int M, int N, int K,
               const float* __restrict__ bias, const u16* __restrict__ resid,
               float* __restrict__ outf, u16* __restrict__ outb,
               u16* __restrict__ qo, u16* __restrict__ ko, u16* __restrict__ vo)
{
  __shared__ __align__(16) u16 Ash[2][256 * 64];
  __shared__ __align__(16) u16 Bsh[2][BR * 64 * 64];
  const int t = threadIdx.x, w = t >> 6, l = t & 63, lg = l >> 4, lr = l & 15;
  const int wr = w >> 2, wc = w & 3;

  const int gx = gridDim.x;
  const int nwg = gx * gridDim.y;
  const int bid = blockIdx.y * gx + blockIdx.x;
  const int cpx = nwg >> 3;
  const int virt = (bid & 7) * cpx + (bid >> 3);
  const int bn0 = (virt % gx) * (BR * 64), bm0 = (virt / gx) * 256;

  f32x4 acc[8][BR] = {};

  const int srow = t >> 3;
  const int sc16 = (t & 7) ^ (srow & 7);
  const u16* gAs = A  + (size_t)(bm0 + srow) * K + sc16 * 8;
  const u16* gBs = Bt + (size_t)(bn0 + srow) * K + sc16 * 8;

#define ISS2_A(R, BUF, ko) GLOAD_LDS16(gAs + (size_t)(R) * 64 * K + (ko), &Ash[BUF][(R) * 4096 + w * 512])
#define ISS2_B(R, BUF, ko) GLOAD_LDS16(gBs + (size_t)(R) * 64 * K + (ko), &Bsh[BUF][(R) * 4096 + w * 512])

  const int nkt = K >> 6;
  ISS2_A(0, 0, 0); ISS2_A(1, 0, 0); ISS2_A(2, 0, 0); ISS2_A(3, 0, 0);
#pragma unroll
  for (int r = 0; r < BR; ++r) ISS2_B(r, 0, 0);
  if (nkt > 1) {
    ISS2_A(0, 1, 64); ISS2_A(2, 1, 64);
    asm volatile("s_waitcnt vmcnt(2)" ::: "memory");
  } else {
    asm volatile("s_waitcnt vmcnt(0)" ::: "memory");
  }
  BARSB();

  auto rdA0k = [&](int buf, int m) -> bf16x8 {
    const int r = wr * 128 + m * 16 + lr;
    return *(const bf16x8*)((const char*)&Ash[buf][0] + r * 128 + (((0 + lg) ^ (r & 7)) << 4));
  };
  auto rdA1k = [&](int buf, int m) -> bf16x8 {
    const int r = wr * 128 + m * 16 + lr;
    return *(const bf16x8*)((const char*)&Ash[buf][0] + r * 128 + (((4 + lg) ^ (r & 7)) << 4));
  };
  auto rdB0k = [&](int buf, int n) -> bf16x8 {
    const int r = wc * (BR * 16) + n * 16 + lr;
    return *(const bf16x8*)((const char*)&Bsh[buf][0] + r * 128 + (((0 + lg) ^ (r & 7)) << 4));
  };
  auto rdB1k = [&](int buf, int n) -> bf16x8 {
    const int r = wc * (BR * 16) + n * 16 + lr;
    return *(const bf16x8*)((const char*)&Bsh[buf][0] + r * 128 + (((4 + lg) ^ (r & 7)) << 4));
  };

  bf16x8 afr[4][2], bfr[BR][2];

  for (int i = 0; i < nkt; ++i) {
    const int buf = i & 1, nb = buf ^ 1;
    const size_t k1 = (size_t)(i + 1) << 6, k2 = (size_t)(i + 2) << 6;
    const bool n1 = (i + 1 < nkt), n2 = (i + 2 < nkt);

    // ---- ph1: read A m0-3 + all B; issue A1,A3 + B0..B(BR-1) (t+1); MFMA (m0-3 x all n) ----
#pragma unroll
    for (int m = 0; m < 4; ++m) { afr[m][0] = rdA0k(buf, m); afr[m][1] = rdA1k(buf, m); }
#pragma unroll
    for (int n = 0; n < BR; ++n) { bfr[n][0] = rdB0k(buf, n); bfr[n][1] = rdB1k(buf, n); }
    if (n1) {
      ISS2_A(1, nb, k1); ISS2_A(3, nb, k1);
#pragma unroll
      for (int r = 0; r < BR; ++r) ISS2_B(r, nb, k1);
    }
    __builtin_amdgcn_s_setprio(1);
#pragma unroll
    for (int m = 0; m < 4; ++m)
#pragma unroll
      for (int n = 0; n < BR; ++n) {
        acc[m][n] = mfma16(afr[m][0], bfr[n][0], acc[m][n]);
        acc[m][n] = mfma16(afr[m][1], bfr[n][1], acc[m][n]);
      }
    __builtin_amdgcn_s_setprio(0);
    BARSB();

    // ---- ph2: read A m4-7; issue A0,A2(t+2); MFMA (m4-7 x all n) ----
#pragma unroll
    for (int m = 0; m < 4; ++m) { afr[m][0] = rdA0k(buf, 4 + m); afr[m][1] = rdA1k(buf, 4 + m); }
    if (n2) { ISS2_A(0, buf, k2); ISS2_A(2, buf, k2); }
    __builtin_amdgcn_s_setprio(1);
#pragma unroll
    for (int m = 0; m < 4; ++m)
#pragma unroll
      for (int n = 0; n < BR; ++n) {
        acc[4 + m][n] = mfma16(afr[m][0], bfr[n][0], acc[4 + m][n]);
        acc[4 + m][n] = mfma16(afr[m][1], bfr[n][1], acc[4 + m][n]);
      }
    __builtin_amdgcn_s_setprio(0);
    if (n1) {
      if (n2) asm volatile("s_waitcnt vmcnt(2)" ::: "memory");
      else    asm volatile("s_waitcnt vmcnt(0)" ::: "memory");
      BARSB();
    }
  }
#undef ISS2_A
#undef ISS2_B

#pragma unroll
  for (int m = 0; m < 8; ++m) {
#pragma unroll
    for (int n = 0; n < BR; ++n) {
#pragma unroll
      for (int r = 0; r < 4; ++r) {
        const int row = bm0 + wr * 128 + m * 16 + lg * 4 + r;
        const int col = bn0 + wc * (BR * 16) + n * 16 + lr;
        float v = acc[m][n][r];
        if constexpr (MODE == MODE_QKV) {   // N=2048: Q,K only
          const int sel = col >> 10, hh = (col >> 6) & 15, dh = col & 63;
          const int bi = row >> 11, tt = row & 2047;
          u16* dst = (sel == 0) ? qo : ko;
          dst[(((size_t)bi * H_ + hh) * T_ + tt) * DH_ + dh] = f2bf(v);
        } else if constexpr (MODE == MODE_VT) {  // C[dh_glob][t_glob] -> vtb[bh][dh][T]
          const int hh = row >> 6, dh = row & 63;
          const int bi = col >> 11, tt = col & 2047;
          outb[(((size_t)bi * H_ + hh) * DH_ + dh) * T_ + tt] = f2bf(v);
        } else if constexpr (MODE == MODE_MLP1) {
          v += bias[col];
          outb[(size_t)row * N + col] = f2bf(v > 0.f ? v : 0.f);
        } else if constexpr (MODE == MODE_WP) {
          v += bias[col] + bf2f(resid[(size_t)row * N + col]);
          outb[(size_t)row * N + col] = f2bf(v);
        } else if constexpr (MODE == MODE_MLP2) {
          outf[(size_t)row * N + col] = v + bias[col] + bf2f(resid[(size_t)row * N + col]);
        }
      }
    }
  }
}

// ---------------- Flash attention: paired q-tiles (qt_hi + qt_lo), KVBLK=64, 8 waves ----
// Every block does exactly 34 KV-steps -> uniform makespan. 512 blocks.
__global__ __launch_bounds__(512, 4)
void attn_kernel(const u16* __restrict__ q, const u16* __restrict__ k,
                 const u16* __restrict__ vt, u16* __restrict__ out)
{
  __shared__ __align__(16) u16 Ks[2][4096];   // [s=64][dh=64], chunk-swizzled (^(s&7))
  __shared__ __align__(16) u16 Vs[2][4096];   // [dh=64][s=64], chunk-swizzled (^(dh&7))
  const int t = threadIdx.x, w = t >> 6, l = t & 63, lg = l >> 4, lr = l & 15;

  const int bid = blockIdx.x;
  const int xcd = bid & 7, vv = bid >> 3;
  const int bh = xcd * 8 + (vv & 7);
  const int pair = vv >> 3;                   // 0..7

  const int b = bh >> 4, h = bh & 15;
  const u16* Qp  = q  + (size_t)bh * T_ * DH_;
  const u16* Kp  = k  + (size_t)bh * T_ * DH_;
  const u16* Vtp = vt + (size_t)bh * T_ * DH_;   // [dh][T]

  const int srow = t >> 3;
  const int schunk = ((t & 7) ^ (srow & 7)) << 3;
  const u16* Kg = Kp  + (size_t)srow * DH_ + schunk;
  const u16* Vg = Vtp + (size_t)srow * T_  + schunk;

  const float SC2 = 0.03125f * 1.44269504f;
  const float THR2 = 11.5416f;
  const size_t obase = ((size_t)b * T_) * D_ + (size_t)h * DH_;

#pragma unroll 1
  for (int pass = 0; pass < 2; ++pass) {
    const int qt = pass == 0 ? (15 - pair) : pair;   // long tile first
    const int qrow = qt * 128 + w * 16 + lr;
    bf16x8 qf0 = *(const bf16x8*)&Qp[(size_t)qrow * DH_ + lg * 8];
    bf16x8 qf1 = *(const bf16x8*)&Qp[(size_t)qrow * DH_ + 32 + lg * 8];
    {  // pre-scale Q by SC2
      union { bf16x8 v8; u16 u[8]; unsigned wd[4]; } a0, a1, r0, r1;
      a0.v8 = qf0; a1.v8 = qf1;
#pragma unroll
      for (int j = 0; j < 4; ++j) {
        unsigned pk;
        float lo = bf2f(a0.u[2 * j]) * SC2, hi = bf2f(a0.u[2 * j + 1]) * SC2;
        CVTPK(pk, lo, hi); r0.wd[j] = pk;
        lo = bf2f(a1.u[2 * j]) * SC2; hi = bf2f(a1.u[2 * j + 1]) * SC2;
        CVTPK(pk, lo, hi); r1.wd[j] = pk;
      }
      qf0 = r0.v8; qf1 = r1.v8;
    }

    float m_run = -1e30f, l_run = 0.f;
    f32x4 o[4] = {};

    GLOAD_LDS16(Kg, &Ks[0][w * 512]);
    GLOAD_LDS16(Vg, &Vs[0][w * 512]);
    __syncthreads();

    const int nst = 2 * qt + 2;
    for (int st = 0; st < nst; ++st) {
      const int cur = st & 1, nxt = cur ^ 1;
      const bool pf = (st + 1 < nst);
      if (pf) {
        GLOAD_LDS16(Kg + (size_t)(st + 1) * 64 * DH_, &Ks[nxt][w * 512]);
        GLOAD_LDS16(Vg + (size_t)(st + 1) * 64,       &Vs[nxt][w * 512]);
      }

      // S^T = K * Q^T : lane holds S[s = n*16+lg*4+r][q = lr] (Q pre-scaled)
      f32x4 sa[4] = {};
      const char* kb = (const char*)&Ks[cur][0];
      __builtin_amdgcn_s_setprio(1);
#pragma unroll
      for (int n = 0; n < 4; ++n) {
        const int sr = n * 16 + lr;
        const int base = (sr << 7) + (lg << 4);
        const int swz = (sr & 7) << 4;
        const bf16x8 b0 = *(const bf16x8*)(kb + (base ^ swz));
        const bf16x8 b1 = *(const bf16x8*)(kb + ((base + 64) ^ swz));
        sa[n] = mfma16(b0, qf0, sa[n]);
        sa[n] = mfma16(b1, qf1, sa[n]);
      }
      __builtin_amdgcn_s_setprio(0);

      if (st >= 2 * qt) {  // diagonal region (uniform branch)
#pragma unroll
        for (int n = 0; n < 4; ++n)
#pragma unroll
          for (int r = 0; r < 4; ++r)
            if (st * 64 + n * 16 + lg * 4 + r > qrow) sa[n][r] = -1e30f;
      }
      float rm = -1e30f;
#pragma unroll
      for (int n = 0; n < 4; ++n)
#pragma unroll
        for (int r = 0; r < 4; ++r)
          rm = fmaxf(rm, sa[n][r]);
      rm = fmaxf(rm, __shfl_xor(rm, 16));
      rm = fmaxf(rm, __shfl_xor(rm, 32));
      const bool noresc = __all(rm <= m_run + THR2);
      if (!noresc) {
        const float mnew = fmaxf(m_run, rm);
        const float al = exp2f(m_run - mnew);
        m_run = mnew;
        l_run *= al;
        const float alr0 = __shfl(al, lg * 4 + 0);
        const float alr1 = __shfl(al, lg * 4 + 1);
        const float alr2 = __shfl(al, lg * 4 + 2);
        const float alr3 = __shfl(al, lg * 4 + 3);
#pragma unroll
        for (int n = 0; n < 4; ++n) {
          o[n][0] *= alr0; o[n][1] *= alr1; o[n][2] *= alr2; o[n][3] *= alr3;
        }
      }
      float rs = 0.f;
#pragma unroll
      for (int n = 0; n < 4; ++n)
#pragma unroll
        for (int r = 0; r < 4; ++r) {
          sa[n][r] = exp2f(sa[n][r] - m_run);   // sa becomes P in place
          rs += sa[n][r];
        }
      rs += __shfl_xor(rs, 16);
      rs += __shfl_xor(rs, 32);
      l_run += rs;

      unsigned pk0a, pk0b, pk1a, pk1b, pk2a, pk2b, pk3a, pk3b;
      CVTPK(pk0a, sa[0][0], sa[0][1]); CVTPK(pk0b, sa[0][2], sa[0][3]);
      CVTPK(pk1a, sa[1][0], sa[1][1]); CVTPK(pk1b, sa[1][2], sa[1][3]);
      CVTPK(pk2a, sa[2][0], sa[2][1]); CVTPK(pk2b, sa[2][2], sa[2][3]);
      CVTPK(pk3a, sa[3][0], sa[3][1]); CVTPK(pk3b, sa[3][2], sa[3][3]);

      const int srcA = lr + ((l >> 4) & 1) * 32;
      const int srcB = srcA + 16;
      const bool hi = (l >> 5) & 1;
      union { uint4 u; bf16x8 v8; } f0, f1;
      {
        const unsigned xA0 = __shfl(pk0a, srcA), xA1 = __shfl(pk0b, srcA);
        const unsigned yA0 = __shfl(pk1a, srcA), yA1 = __shfl(pk1b, srcA);
        const unsigned xB0 = __shfl(pk0a, srcB), xB1 = __shfl(pk0b, srcB);
        const unsigned yB0 = __shfl(pk1a, srcB), yB1 = __shfl(pk1b, srcB);
        f0.u.x = hi ? yA0 : xA0; f0.u.y = hi ? yA1 : xA1;
        f0.u.z = hi ? yB0 : xB0; f0.u.w = hi ? yB1 : xB1;
      }
      {
        const unsigned xA0 = __shfl(pk2a, srcA), xA1 = __shfl(pk2b, srcA);
        const unsigned yA0 = __shfl(pk3a, srcA), yA1 = __shfl(pk3b, srcA);
        const unsigned xB0 = __shfl(pk2a, srcB), xB1 = __shfl(pk2b, srcB);
        const unsigned yB0 = __shfl(pk3a, srcB), yB1 = __shfl(pk3b, srcB);
        f1.u.x = hi ? yA0 : xA0; f1.u.y = hi ? yA1 : xA1;
        f1.u.z = hi ? yB0 : xB0; f1.u.w = hi ? yB1 : xB1;
      }

      // O += P * V   (V^T fragments: row = dh, chunk-swizzled)
      const char* vbase = (const char*)&Vs[cur][0];
      __builtin_amdgcn_s_setprio(1);
#pragma unroll
      for (int ks = 0; ks < 2; ++ks) {
        const bf16x8 pa = ks ? f1.v8 : f0.v8;
#pragma unroll
        for (int n = 0; n < 4; ++n) {
          const int dh = n * 16 + lr;
          const int base = (dh << 7) + (ks << 6) + (lg << 4);
          const int swz = (dh & 7) << 4;
          const bf16x8 vbf = *(const bf16x8*)(vbase + (base ^ swz));
          o[n] = mfma16(pa, vbf, o[n]);
        }
      }
      __builtin_amdgcn_s_setprio(0);

      __syncthreads();
    }

    float li[4];
    li[0] = 1.0f / __shfl(l_run, lg * 4 + 0);
    li[1] = 1.0f / __shfl(l_run, lg * 4 + 1);
    li[2] = 1.0f / __shfl(l_run, lg * 4 + 2);
    li[3] = 1.0f / __shfl(l_run, lg * 4 + 3);
#pragma unroll
    for (int n = 0; n < 4; ++n) {
#pragma unroll
      for (int r = 0; r < 4; ++r) {
        const int qg = qt * 128 + w * 16 + lg * 4 + r;
        out[obase + (size_t)qg * D_ + n * 16 + lr] = f2bf(o[n][r] * li[r]);
      }
    }
    __syncthreads();   // pass boundary: all LDS reads done before re-staging
  }
}

// ---------------- host ----------------
extern "C" void kernel_launch(void* const* d_in, const int* in_sizes, int n_in,
                              void* d_out, int out_size, void* d_ws, size_t ws_size,
                              hipStream_t stream) {
  (void)in_sizes; (void)n_in; (void)out_size; (void)ws_size;
  const float* x   = (const float*)d_in[0];
  const float* Wq  = (const float*)d_in[2];
  const float* Wk  = (const float*)d_in[3];
  const float* Wv  = (const float*)d_in[4];
  const float* Wp  = (const float*)d_in[5];
  const float* bp  = (const float*)d_in[6];
  const float* W1  = (const float*)d_in[7];
  const float* b1  = (const float*)d_in[8];
  const float* W2  = (const float*)d_in[9];
  const float* b2  = (const float*)d_in[10];
  const float* g1  = (const float*)d_in[11];
  const float* be1 = (const float*)d_in[12];
  const float* g2  = (const float*)d_in[13];
  const float* be2 = (const float*)d_in[14];

  char* ws = (char*)d_ws;
  const size_t MB16 = 16777216;
  u16* x1b   = (u16*)(ws);
  u16* qb    = (u16*)(ws + 1 * MB16);
  u16* kb    = (u16*)(ws + 2 * MB16);
  u16* attnb = (u16*)(ws + 4 * MB16);
  u16* x2b   = (u16*)(ws + 5 * MB16);
  u16* hb    = (u16*)(ws + 6 * MB16);
  u16* vtb   = (u16*)(ws + 3 * MB16);      // V^T [bh][64][2048]
  u16* wqkvb = (u16*)(ws + 10 * MB16);
  u16* wpb   = (u16*)(ws + 10 * MB16 + 6291456);
  u16* w1b   = (u16*)(ws + 10 * MB16 + 8388608);
  u16* w2b   = (u16*)(ws + 11 * MB16);
  u16* x3b   = qb;

  dim3 tb(32, 8, 1);
  transpose_cvt3<<<dim3(2, 32, 48),  tb, 0, stream>>>(Wq, Wk, Wv, wqkvb);
  transpose_cvt<<<dim3(32, 32, 1),  tb, 0, stream>>>(Wp, wpb, 1024, 1024);
  transpose_cvt<<<dim3(128, 32, 1), tb, 0, stream>>>(W1, w1b, 1024, 4096);
  transpose_cvt<<<dim3(32, 128, 1), tb, 0, stream>>>(W2, w2b, 4096, 1024);

  ln_kernel<float><<<8192, 256, 0, stream>>>(x, g1, be1, x1b);

  // Q,K: C[8192 t][2048 qk] — 256 blocks = 1 perfect round
  gemm256v3<MODE_QKV, 4><<<dim3(8, 32), 512, 0, stream>>>(
      x1b, wqkvb, 8192, 2048, 1024, nullptr, nullptr, nullptr, nullptr, qb, kb, nullptr);

  // V^T: A = Wv^T [1024 dh][1024 k], Bt = x1b [8192 t][1024 k]; BR=2 -> 256 blocks = 1 round
  gemm256v3<MODE_VT, 2><<<dim3(64, 4), 512, 0, stream>>>(
      wqkvb + (size_t)2097152, x1b, 1024, 8192, 1024,
      nullptr, nullptr, nullptr, vtb, nullptr, nullptr, nullptr);

  attn_kernel<<<dim3(512), 512, 0, stream>>>(qb, kb, vtb, attnb);

  gemm256v3<MODE_WP, 2><<<dim3(8, 32), 512, 0, stream>>>(
      attnb, wpb, 8192, 1024, 1024, bp, x1b, nullptr, x2b, nullptr, nullptr, nullptr);

  ln_kernel<u16><<<8192, 256, 0, stream>>>(x2b, g2, be2, x3b);

  gemm256v3<MODE_MLP1, 4><<<dim3(16, 32), 512, 0, stream>>>(
      x3b, w1b, 8192, 4096, 1024, b1, nullptr, nullptr, hb, nullptr, nullptr, nullptr);

  gemm256v3<MODE_MLP2, 2><<<dim3(8, 32), 512, 0, stream>>>(
      hb, w2b, 8192, 1024, 4096, b2, x3b, (float*)d_out, nullptr, nullptr, nullptr, nullptr);
}